// Round 2
// baseline (204.392 us; speedup 1.0000x reference)
//
#include <hip/hip_runtime.h>
#include <hip/hip_bf16.h>
#include <cstddef>

typedef __attribute__((ext_vector_type(8))) short short8;
typedef __attribute__((ext_vector_type(4))) float floatx4;
typedef __hip_bfloat16 bf16;

#define NB 8
#define NC 256
#define ND 128
#define NN 3072
#define BN_EPS 1e-5f

static __device__ __forceinline__ short f2s(float v) {
    bf16 h = __float2bfloat16(v);
    return *reinterpret_cast<short*>(&h);
}

// Convert fp32 weights to bf16 workspace:
//   WPG (256x256) = [phi_w; g_w],  thW (128x256) = theta_w
// and fold BN: inv = gamma/sqrt(var+eps); bias2 = inv*(w_b-mean)+beta;
// bcat = [phi_b; g_b] (f32).
__global__ __launch_bounds__(256) void prep_kernel(
    const float* __restrict__ phi_w, const float* __restrict__ g_w,
    const float* __restrict__ theta_w,
    const float* __restrict__ phi_b, const float* __restrict__ g_b,
    const float* __restrict__ w_b, const float* __restrict__ gamma,
    const float* __restrict__ beta, const float* __restrict__ mean,
    const float* __restrict__ var,
    short* __restrict__ WPG, short* __restrict__ thW,
    float* __restrict__ bcat, float* __restrict__ invv,
    float* __restrict__ bias2)
{
    int t = threadIdx.x;        // 0..255 (channel c)
    int r = blockIdx.x;         // 0..383
    if (r < NC) {
        const float* src = (r < ND) ? (phi_w + (size_t)r * NC)
                                    : (g_w + (size_t)(r - ND) * NC);
        WPG[(size_t)r * NC + t] = f2s(src[t]);
    } else {
        thW[(size_t)(r - NC) * NC + t] = f2s(theta_w[(size_t)(r - NC) * NC + t]);
    }
    if (r == 0) {
        bcat[t] = (t < ND) ? phi_b[t] : g_b[t - ND];
        float iv = gamma[t] * rsqrtf(var[t] + BN_EPS);
        invv[t] = iv;
        bias2[t] = iv * (w_b[t] - mean[t]) + beta[t];
    }
}

// x fp32 (B,C,N) -> xT bf16 (B,N,C). 64x64 tiles via LDS (pad 68 shorts).
__global__ __launch_bounds__(256) void transpose_kernel(
    const float* __restrict__ x, short* __restrict__ xT)
{
    __shared__ short tile[64][68];
    int b = blockIdx.z;
    int n0 = blockIdx.x * 64, c0 = blockIdx.y * 64;
    int t = threadIdx.x;
    int ch = (t & 7) * 8;
    int r0 = t >> 3;            // 0..31
#pragma unroll
    for (int p = 0; p < 2; ++p) {
        int c = r0 + p * 32;
        const float* src = x + ((size_t)b * NC + c0 + c) * NN + n0 + ch;
        floatx4 v0 = *(const floatx4*)(src);
        floatx4 v1 = *(const floatx4*)(src + 4);
#pragma unroll
        for (int j = 0; j < 4; ++j) {
            tile[c][ch + j]     = f2s(v0[j]);
            tile[c][ch + 4 + j] = f2s(v1[j]);
        }
    }
    __syncthreads();
#pragma unroll
    for (int p = 0; p < 2; ++p) {
        int n = r0 + p * 32;
        short8 v;
#pragma unroll
        for (int j = 0; j < 8; ++j) v[j] = tile[ch + j][n];
        *(short8*)(xT + ((size_t)b * NN + n0 + n) * NC + c0 + ch) = v;
    }
}

// C(M,N) = A(M,K) . B(N,K)^T  (bf16 operands, K contiguous), per-batch
// strides sA/sB/sC/sR in elements. 128x128 tile, 4 waves (2x2 of 64x64),
// BK=64, mfma_f32_16x16x32_bf16, fp32 accumulate.
// mode 0: bf16 out, + f32 bias[row]
// mode 1: bf16 out, + f32 bias[col]
// mode 2: f32 out, * scale
// mode 3: f32 out, + f32 bias[row] + f32 resid[row*N+col]  (final output)
__global__ __launch_bounds__(256)
void bt_gemm(const short* __restrict__ Ag0, const short* __restrict__ Bg0,
             void* __restrict__ Cout, const float* __restrict__ bias,
             const float* __restrict__ resid,
             int M, int N, int K,
             long sA, long sB, long sC, long sR,
             int mode, float scale)
{
    __shared__ short As[128][72];
    __shared__ short Bs[128][72];
    int b = blockIdx.z;
    const short* Ag = Ag0 + (size_t)b * sA;
    const short* Bg = Bg0 + (size_t)b * sB;
    int tile_m = blockIdx.y * 128;
    int tile_n = blockIdx.x * 128;
    int t = threadIdx.x;
    int lane = t & 63;
    int wave = t >> 6;
    int wr = wave >> 1, wc = wave & 1;
    int lm = lane & 15;             // A row / B col within 16
    int lk = (lane >> 4) * 8;       // k sub-offset
    int ch = (t & 7) * 8;
    int r0 = t >> 3;

    floatx4 zero = {0.f, 0.f, 0.f, 0.f};
    floatx4 acc[4][4];
#pragma unroll
    for (int i = 0; i < 4; ++i)
#pragma unroll
        for (int j = 0; j < 4; ++j) acc[i][j] = zero;

    for (int kt = 0; kt < K; kt += 64) {
        __syncthreads();
#pragma unroll
        for (int p = 0; p < 4; ++p) {
            int r = r0 + p * 32;
            *(short8*)&As[r][ch] = *(const short8*)(Ag + (size_t)(tile_m + r) * K + kt + ch);
            *(short8*)&Bs[r][ch] = *(const short8*)(Bg + (size_t)(tile_n + r) * K + kt + ch);
        }
        __syncthreads();
#pragma unroll
        for (int kk = 0; kk < 64; kk += 32) {
            short8 af[4], bfr[4];
#pragma unroll
            for (int i = 0; i < 4; ++i)
                af[i] = *(const short8*)&As[wr * 64 + i * 16 + lm][kk + lk];
#pragma unroll
            for (int j = 0; j < 4; ++j)
                bfr[j] = *(const short8*)&Bs[wc * 64 + j * 16 + lm][kk + lk];
#pragma unroll
            for (int i = 0; i < 4; ++i)
#pragma unroll
                for (int j = 0; j < 4; ++j)
                    acc[i][j] = __builtin_amdgcn_mfma_f32_16x16x32_bf16(
                        af[i], bfr[j], acc[i][j], 0, 0, 0);
        }
    }

    // C/D layout (verified m89/m91): col = lane&15, row = (lane>>4)*4 + reg
    int row0 = tile_m + wr * 64 + (lane >> 4) * 4;
    int col0 = tile_n + wc * 64 + lm;

    if (mode == 2) {
        float* Cf = (float*)Cout + (size_t)b * sC;
#pragma unroll
        for (int i = 0; i < 4; ++i)
#pragma unroll
            for (int j = 0; j < 4; ++j)
#pragma unroll
                for (int r = 0; r < 4; ++r)
                    Cf[(size_t)(row0 + i * 16 + r) * N + col0 + j * 16] = acc[i][j][r] * scale;
    } else if (mode == 0) {
        short* Cb = (short*)Cout + (size_t)b * sC;
#pragma unroll
        for (int i = 0; i < 4; ++i) {
#pragma unroll
            for (int r = 0; r < 4; ++r) {
                int row = row0 + i * 16 + r;
                float bv = bias[row];
#pragma unroll
                for (int j = 0; j < 4; ++j)
                    Cb[(size_t)row * N + col0 + j * 16] = f2s(acc[i][j][r] + bv);
            }
        }
    } else if (mode == 1) {
        short* Cb = (short*)Cout + (size_t)b * sC;
        float bcol[4];
#pragma unroll
        for (int j = 0; j < 4; ++j) bcol[j] = bias[col0 + j * 16];
#pragma unroll
        for (int i = 0; i < 4; ++i)
#pragma unroll
            for (int j = 0; j < 4; ++j)
#pragma unroll
                for (int r = 0; r < 4; ++r)
                    Cb[(size_t)(row0 + i * 16 + r) * N + col0 + j * 16] =
                        f2s(acc[i][j][r] + bcol[j]);
    } else { // mode 3: fp32 out = acc + bias2[row] + resid
        float* Cf = (float*)Cout + (size_t)b * sC;
        const float* Rg = resid + (size_t)b * sR;
#pragma unroll
        for (int i = 0; i < 4; ++i) {
#pragma unroll
            for (int r = 0; r < 4; ++r) {
                int row = row0 + i * 16 + r;
                float bv = bias[row];
#pragma unroll
                for (int j = 0; j < 4; ++j) {
                    size_t idx = (size_t)row * N + col0 + j * 16;
                    Cf[idx] = acc[i][j][r] + bv + Rg[idx];
                }
            }
        }
    }
}

// P2[b][c][e] = inv[c] * (1) * sum_d w_w[c][d] * Mbuf[b][e][d]   (bf16 out)
__global__ __launch_bounds__(256)
void p2_kernel(const float* __restrict__ w_w, const float* __restrict__ Mbuf,
               const float* __restrict__ invv, short* __restrict__ P2)
{
    int b = blockIdx.y;
    int t = threadIdx.x;
    int c = blockIdx.x * 2 + (t >> 7);
    int e = t & 127;
    const float* wrow = w_w + (size_t)c * ND;
    const float* Mr = Mbuf + (size_t)b * ND * ND + (size_t)e * ND;
    float s = 0.f;
#pragma unroll 4
    for (int d = 0; d < ND; ++d) s += wrow[d] * Mr[d];
    P2[(size_t)b * NC * ND + (size_t)c * ND + e] = f2s(s * invv[c]);
}

extern "C" void kernel_launch(void* const* d_in, const int* in_sizes, int n_in,
                              void* d_out, int out_size, void* d_ws, size_t ws_size,
                              hipStream_t stream)
{
    const float* x       = (const float*)d_in[0];
    const float* g_w     = (const float*)d_in[1];
    const float* g_b     = (const float*)d_in[2];
    const float* theta_w = (const float*)d_in[3];
    const float* theta_b = (const float*)d_in[4];
    const float* phi_w   = (const float*)d_in[5];
    const float* phi_b   = (const float*)d_in[6];
    const float* w_w     = (const float*)d_in[7];
    const float* w_b     = (const float*)d_in[8];
    const float* gamma   = (const float*)d_in[9];
    const float* beta    = (const float*)d_in[10];
    const float* mean    = (const float*)d_in[11];
    const float* var     = (const float*)d_in[12];
    (void)in_sizes; (void)n_in; (void)out_size; (void)ws_size;

    char* w = (char*)d_ws;
    short* WPG   = (short*)w; w += (size_t)NC * NC * 2;
    short* thW   = (short*)w; w += (size_t)ND * NC * 2;
    float* bcat  = (float*)w; w += (size_t)NC * 4;
    float* invv  = (float*)w; w += (size_t)NC * 4;
    float* bias2 = (float*)w; w += (size_t)NC * 4;
    w = (char*)(((size_t)w + 255) & ~(size_t)255);
    short* xT    = (short*)w; w += (size_t)NB * NN * NC * 2;   // (B,N,C) bf16
    short* projPG= (short*)w; w += (size_t)NB * NC * NN * 2;   // (B,[phi;g],N) bf16
    short* thND  = (short*)w; w += (size_t)NB * NN * ND * 2;   // (B,N,D) bf16
    float* Mbuf  = (float*)w; w += (size_t)NB * ND * ND * 4;   // (B,D,D) f32
    short* P2    = (short*)w; w += (size_t)NB * NC * ND * 2;   // (B,C,D) bf16

    prep_kernel<<<dim3(NC + ND), dim3(NC), 0, stream>>>(
        phi_w, g_w, theta_w, phi_b, g_b, w_b, gamma, beta, mean, var,
        WPG, thW, bcat, invv, bias2);

    transpose_kernel<<<dim3(NN / 64, NC / 64, NB), 256, 0, stream>>>(x, xT);

    // thND (3072x128) = xT (3072x256) . thW^T + theta_b (per col)
    bt_gemm<<<dim3(1, NN / 128, NB), 256, 0, stream>>>(
        xT, thW, thND, theta_b, nullptr,
        NN, ND, NC, (long)NN * NC, 0, (long)NN * ND, 0, 1, 1.f);

    // projPG (256x3072) = WPG (256x256) . xT^T + bcat (per row)
    bt_gemm<<<dim3(NN / 128, NC / 128, NB), 256, 0, stream>>>(
        WPG, xT, projPG, bcat, nullptr,
        NC, NN, NC, 0, (long)NN * NC, (long)NC * NN, 0, 0, 1.f);

    // Mbuf (128x128 f32) = phi (128x3072) . g^T / N
    bt_gemm<<<dim3(1, 1, NB), 256, 0, stream>>>(
        projPG, projPG + (size_t)ND * NN, Mbuf, nullptr, nullptr,
        ND, ND, NN, (long)NC * NN, (long)NC * NN, (long)ND * ND, 0,
        2, 1.f / (float)NN);

    p2_kernel<<<dim3(NC / 2, NB), 256, 0, stream>>>(w_w, Mbuf, invv, P2);

    // out (256x3072 f32) = P2 (256x128) . thND^T + bias2 + x
    bt_gemm<<<dim3(NN / 128, NC / 128, NB), 256, 0, stream>>>(
        P2, thND, d_out, bias2, x,
        NC, NN, ND, (long)NC * ND, (long)NN * ND, (long)NC * NN, (long)NC * NN,
        3, 1.f);
}

// Round 3
// 169.787 us; speedup vs baseline: 1.2038x; 1.2038x over previous
//
#include <hip/hip_runtime.h>
#include <hip/hip_bf16.h>
#include <cstddef>

typedef __attribute__((ext_vector_type(8))) short short8;
typedef __attribute__((ext_vector_type(4))) float floatx4;
typedef __hip_bfloat16 bf16;

#define NB 8
#define NC 256
#define ND 128
#define NN 3072
#define BN_EPS 1e-5f
#define MSPLIT 24   /* K split count for the Mbuf GEMM: 3072/24 = 128 per slice */

static __device__ __forceinline__ short f2s(float v) {
    bf16 h = __float2bfloat16(v);
    return *reinterpret_cast<short*>(&h);
}

// Convert fp32 weights to bf16 workspace:
//   WPG (256x256) = [phi_w; g_w],  thW (128x256) = theta_w
// and fold BN: inv = gamma/sqrt(var+eps); bias2 = inv*(w_b-mean)+beta;
// bcat = [phi_b; g_b] (f32).
__global__ __launch_bounds__(256) void prep_kernel(
    const float* __restrict__ phi_w, const float* __restrict__ g_w,
    const float* __restrict__ theta_w,
    const float* __restrict__ phi_b, const float* __restrict__ g_b,
    const float* __restrict__ w_b, const float* __restrict__ gamma,
    const float* __restrict__ beta, const float* __restrict__ mean,
    const float* __restrict__ var,
    short* __restrict__ WPG, short* __restrict__ thW,
    float* __restrict__ bcat, float* __restrict__ invv,
    float* __restrict__ bias2)
{
    int t = threadIdx.x;        // 0..255 (channel c)
    int r = blockIdx.x;         // 0..383
    if (r < NC) {
        const float* src = (r < ND) ? (phi_w + (size_t)r * NC)
                                    : (g_w + (size_t)(r - ND) * NC);
        WPG[(size_t)r * NC + t] = f2s(src[t]);
    } else {
        thW[(size_t)(r - NC) * NC + t] = f2s(theta_w[(size_t)(r - NC) * NC + t]);
    }
    if (r == 0) {
        bcat[t] = (t < ND) ? phi_b[t] : g_b[t - ND];
        float iv = gamma[t] * rsqrtf(var[t] + BN_EPS);
        invv[t] = iv;
        bias2[t] = iv * (w_b[t] - mean[t]) + beta[t];
    }
}

// x fp32 (B,C,N) -> xT bf16 (B,N,C). 64x64 tiles via LDS (pad 68 shorts).
__global__ __launch_bounds__(256) void transpose_kernel(
    const float* __restrict__ x, short* __restrict__ xT)
{
    __shared__ short tile[64][68];
    int b = blockIdx.z;
    int n0 = blockIdx.x * 64, c0 = blockIdx.y * 64;
    int t = threadIdx.x;
    int ch = (t & 7) * 8;
    int r0 = t >> 3;            // 0..31
#pragma unroll
    for (int p = 0; p < 2; ++p) {
        int c = r0 + p * 32;
        const float* src = x + ((size_t)b * NC + c0 + c) * NN + n0 + ch;
        floatx4 v0 = *(const floatx4*)(src);
        floatx4 v1 = *(const floatx4*)(src + 4);
#pragma unroll
        for (int j = 0; j < 4; ++j) {
            tile[c][ch + j]     = f2s(v0[j]);
            tile[c][ch + 4 + j] = f2s(v1[j]);
        }
    }
    __syncthreads();
#pragma unroll
    for (int p = 0; p < 2; ++p) {
        int n = r0 + p * 32;
        short8 v;
#pragma unroll
        for (int j = 0; j < 8; ++j) v[j] = tile[ch + j][n];
        *(short8*)(xT + ((size_t)b * NN + n0 + n) * NC + c0 + ch) = v;
    }
}

// C(M,N) = A(M,K) . B(N,K)^T  (bf16 operands, K contiguous), per-batch
// strides sA/sB/sC/sR in elements. 128x128 tile, 4 waves (2x2 of 64x64),
// BK=64, mfma_f32_16x16x32_bf16, fp32 accumulate.
// mode 0: bf16 out, + f32 bias[row]
// mode 1: bf16 out, + f32 bias[col]
// mode 3: f32 out, + f32 bias[row] + f32 resid[row*N+col]  (final output)
__global__ __launch_bounds__(256)
void bt_gemm(const short* __restrict__ Ag0, const short* __restrict__ Bg0,
             void* __restrict__ Cout, const float* __restrict__ bias,
             const float* __restrict__ resid,
             int M, int N, int K,
             long sA, long sB, long sC, long sR,
             int mode)
{
    __shared__ short As[128][72];
    __shared__ short Bs[128][72];
    int b = blockIdx.z;
    const short* Ag = Ag0 + (size_t)b * sA;
    const short* Bg = Bg0 + (size_t)b * sB;
    int tile_m = blockIdx.y * 128;
    int tile_n = blockIdx.x * 128;
    int t = threadIdx.x;
    int lane = t & 63;
    int wave = t >> 6;
    int wr = wave >> 1, wc = wave & 1;
    int lm = lane & 15;             // A row / B col within 16
    int lk = (lane >> 4) * 8;       // k sub-offset
    int ch = (t & 7) * 8;
    int r0 = t >> 3;

    floatx4 zero = {0.f, 0.f, 0.f, 0.f};
    floatx4 acc[4][4];
#pragma unroll
    for (int i = 0; i < 4; ++i)
#pragma unroll
        for (int j = 0; j < 4; ++j) acc[i][j] = zero;

    for (int kt = 0; kt < K; kt += 64) {
        __syncthreads();
#pragma unroll
        for (int p = 0; p < 4; ++p) {
            int r = r0 + p * 32;
            *(short8*)&As[r][ch] = *(const short8*)(Ag + (size_t)(tile_m + r) * K + kt + ch);
            *(short8*)&Bs[r][ch] = *(const short8*)(Bg + (size_t)(tile_n + r) * K + kt + ch);
        }
        __syncthreads();
#pragma unroll
        for (int kk = 0; kk < 64; kk += 32) {
            short8 af[4], bfr[4];
#pragma unroll
            for (int i = 0; i < 4; ++i)
                af[i] = *(const short8*)&As[wr * 64 + i * 16 + lm][kk + lk];
#pragma unroll
            for (int j = 0; j < 4; ++j)
                bfr[j] = *(const short8*)&Bs[wc * 64 + j * 16 + lm][kk + lk];
#pragma unroll
            for (int i = 0; i < 4; ++i)
#pragma unroll
                for (int j = 0; j < 4; ++j)
                    acc[i][j] = __builtin_amdgcn_mfma_f32_16x16x32_bf16(
                        af[i], bfr[j], acc[i][j], 0, 0, 0);
        }
    }

    // C/D layout (verified m89/m91): col = lane&15, row = (lane>>4)*4 + reg
    int row0 = tile_m + wr * 64 + (lane >> 4) * 4;
    int col0 = tile_n + wc * 64 + lm;

    if (mode == 0) {
        short* Cb = (short*)Cout + (size_t)b * sC;
#pragma unroll
        for (int i = 0; i < 4; ++i) {
#pragma unroll
            for (int r = 0; r < 4; ++r) {
                int row = row0 + i * 16 + r;
                float bv = bias[row];
#pragma unroll
                for (int j = 0; j < 4; ++j)
                    Cb[(size_t)row * N + col0 + j * 16] = f2s(acc[i][j][r] + bv);
            }
        }
    } else if (mode == 1) {
        short* Cb = (short*)Cout + (size_t)b * sC;
        float bcol[4];
#pragma unroll
        for (int j = 0; j < 4; ++j) bcol[j] = bias[col0 + j * 16];
#pragma unroll
        for (int i = 0; i < 4; ++i)
#pragma unroll
            for (int j = 0; j < 4; ++j)
#pragma unroll
                for (int r = 0; r < 4; ++r)
                    Cb[(size_t)(row0 + i * 16 + r) * N + col0 + j * 16] =
                        f2s(acc[i][j][r] + bcol[j]);
    } else { // mode 3: fp32 out = acc + bias2[row] + resid
        float* Cf = (float*)Cout + (size_t)b * sC;
        const float* Rg = resid + (size_t)b * sR;
#pragma unroll
        for (int i = 0; i < 4; ++i) {
#pragma unroll
            for (int r = 0; r < 4; ++r) {
                int row = row0 + i * 16 + r;
                float bv = bias[row];
#pragma unroll
                for (int j = 0; j < 4; ++j) {
                    size_t idx = (size_t)row * N + col0 + j * 16;
                    Cf[idx] = acc[i][j][r] + bv + Rg[idx];
                }
            }
        }
    }
}

// Split-K GEMM for Mbuf: Mbuf[b][i][j] += scale * sum_{k in slice}
//   phi[i][k] * gproj[j][k], slice = blockIdx.x * (NN/MSPLIT).
// grid (MSPLIT, 1, NB) -> 192 blocks (vs 8 before: the 56us fix).
// Mbuf must be zeroed before launch (hipMemsetAsync).
__global__ __launch_bounds__(256)
void mbuf_split(const short* __restrict__ projPG, float* __restrict__ Mbuf,
                float scale)
{
    __shared__ short As[128][72];
    __shared__ short Bs[128][72];
    int b = blockIdx.z;
    const short* Ag = projPG + (size_t)b * NC * NN;          // phi rows (D x N)
    const short* Bg = Ag + (size_t)ND * NN;                  // g-proj rows (D x N)
    int kt0 = blockIdx.x * (NN / MSPLIT);
    int t = threadIdx.x;
    int lane = t & 63;
    int wave = t >> 6;
    int wr = wave >> 1, wc = wave & 1;
    int lm = lane & 15;
    int lk = (lane >> 4) * 8;
    int ch = (t & 7) * 8;
    int r0 = t >> 3;

    floatx4 zero = {0.f, 0.f, 0.f, 0.f};
    floatx4 acc[4][4];
#pragma unroll
    for (int i = 0; i < 4; ++i)
#pragma unroll
        for (int j = 0; j < 4; ++j) acc[i][j] = zero;

    for (int kt = kt0; kt < kt0 + NN / MSPLIT; kt += 64) {
        __syncthreads();
#pragma unroll
        for (int p = 0; p < 4; ++p) {
            int r = r0 + p * 32;
            *(short8*)&As[r][ch] = *(const short8*)(Ag + (size_t)r * NN + kt + ch);
            *(short8*)&Bs[r][ch] = *(const short8*)(Bg + (size_t)r * NN + kt + ch);
        }
        __syncthreads();
#pragma unroll
        for (int kk = 0; kk < 64; kk += 32) {
            short8 af[4], bfr[4];
#pragma unroll
            for (int i = 0; i < 4; ++i)
                af[i] = *(const short8*)&As[wr * 64 + i * 16 + lm][kk + lk];
#pragma unroll
            for (int j = 0; j < 4; ++j)
                bfr[j] = *(const short8*)&Bs[wc * 64 + j * 16 + lm][kk + lk];
#pragma unroll
            for (int i = 0; i < 4; ++i)
#pragma unroll
                for (int j = 0; j < 4; ++j)
                    acc[i][j] = __builtin_amdgcn_mfma_f32_16x16x32_bf16(
                        af[i], bfr[j], acc[i][j], 0, 0, 0);
        }
    }

    float* Mf = Mbuf + (size_t)b * ND * ND;
    int row0 = wr * 64 + (lane >> 4) * 4;
    int col0 = wc * 64 + lm;
#pragma unroll
    for (int i = 0; i < 4; ++i)
#pragma unroll
        for (int j = 0; j < 4; ++j)
#pragma unroll
            for (int r = 0; r < 4; ++r)
                atomicAdd(&Mf[(size_t)(row0 + i * 16 + r) * ND + col0 + j * 16],
                          acc[i][j][r] * scale);
}

// P2[b][c][e] = inv[c] * sum_d w_w[c][d] * Mbuf[b][e][d]   (bf16 out)
__global__ __launch_bounds__(256)
void p2_kernel(const float* __restrict__ w_w, const float* __restrict__ Mbuf,
               const float* __restrict__ invv, short* __restrict__ P2)
{
    int b = blockIdx.y;
    int t = threadIdx.x;
    int c = blockIdx.x * 2 + (t >> 7);
    int e = t & 127;
    const float* wrow = w_w + (size_t)c * ND;
    const float* Mr = Mbuf + (size_t)b * ND * ND + (size_t)e * ND;
    float s = 0.f;
#pragma unroll 4
    for (int d = 0; d < ND; ++d) s += wrow[d] * Mr[d];
    P2[(size_t)b * NC * ND + (size_t)c * ND + e] = f2s(s * invv[c]);
}

extern "C" void kernel_launch(void* const* d_in, const int* in_sizes, int n_in,
                              void* d_out, int out_size, void* d_ws, size_t ws_size,
                              hipStream_t stream)
{
    const float* x       = (const float*)d_in[0];
    const float* g_w     = (const float*)d_in[1];
    const float* g_b     = (const float*)d_in[2];
    const float* theta_w = (const float*)d_in[3];
    const float* theta_b = (const float*)d_in[4];
    const float* phi_w   = (const float*)d_in[5];
    const float* phi_b   = (const float*)d_in[6];
    const float* w_w     = (const float*)d_in[7];
    const float* w_b     = (const float*)d_in[8];
    const float* gamma   = (const float*)d_in[9];
    const float* beta    = (const float*)d_in[10];
    const float* mean    = (const float*)d_in[11];
    const float* var     = (const float*)d_in[12];
    (void)in_sizes; (void)n_in; (void)out_size; (void)ws_size;

    char* w = (char*)d_ws;
    short* WPG   = (short*)w; w += (size_t)NC * NC * 2;
    short* thW   = (short*)w; w += (size_t)ND * NC * 2;
    float* bcat  = (float*)w; w += (size_t)NC * 4;
    float* invv  = (float*)w; w += (size_t)NC * 4;
    float* bias2 = (float*)w; w += (size_t)NC * 4;
    w = (char*)(((size_t)w + 255) & ~(size_t)255);
    short* xT    = (short*)w; w += (size_t)NB * NN * NC * 2;   // (B,N,C) bf16
    short* projPG= (short*)w; w += (size_t)NB * NC * NN * 2;   // (B,[phi;g],N) bf16
    short* thND  = (short*)w; w += (size_t)NB * NN * ND * 2;   // (B,N,D) bf16
    float* Mbuf  = (float*)w; w += (size_t)NB * ND * ND * 4;   // (B,D,D) f32
    short* P2    = (short*)w; w += (size_t)NB * NC * ND * 2;   // (B,C,D) bf16

    // Zero the split-K accumulator (capture-legal memset node).
    hipMemsetAsync(Mbuf, 0, (size_t)NB * ND * ND * 4, stream);

    prep_kernel<<<dim3(NC + ND), dim3(NC), 0, stream>>>(
        phi_w, g_w, theta_w, phi_b, g_b, w_b, gamma, beta, mean, var,
        WPG, thW, bcat, invv, bias2);

    transpose_kernel<<<dim3(NN / 64, NC / 64, NB), 256, 0, stream>>>(x, xT);

    // thND (3072x128) = xT (3072x256) . thW^T + theta_b (per col)
    bt_gemm<<<dim3(1, NN / 128, NB), 256, 0, stream>>>(
        xT, thW, thND, theta_b, nullptr,
        NN, ND, NC, (long)NN * NC, 0, (long)NN * ND, 0, 1);

    // projPG (256x3072) = WPG (256x256) . xT^T + bcat (per row)
    bt_gemm<<<dim3(NN / 128, NC / 128, NB), 256, 0, stream>>>(
        WPG, xT, projPG, bcat, nullptr,
        NC, NN, NC, 0, (long)NN * NC, (long)NC * NN, 0, 0);

    // Mbuf (128x128 f32) = phi (128x3072) . g^T / N   -- split-K, atomics
    mbuf_split<<<dim3(MSPLIT, 1, NB), 256, 0, stream>>>(
        projPG, Mbuf, 1.f / (float)NN);

    p2_kernel<<<dim3(NC / 2, NB), 256, 0, stream>>>(w_w, Mbuf, invv, P2);

    // out (256x3072 f32) = P2 (256x128) . thND^T + bias2 + x
    bt_gemm<<<dim3(NN / 128, NC / 128, NB), 256, 0, stream>>>(
        P2, thND, d_out, bias2, x,
        NC, NN, ND, (long)NC * ND, (long)NN * ND, (long)NC * NN, (long)NC * NN,
        3);
}

// Round 4
// 163.833 us; speedup vs baseline: 1.2476x; 1.0363x over previous
//
#include <hip/hip_runtime.h>
#include <hip/hip_bf16.h>
#include <cstddef>

typedef __attribute__((ext_vector_type(8))) short short8;
typedef __attribute__((ext_vector_type(4))) float floatx4;
typedef __hip_bfloat16 bf16;

#define NB 8
#define NC 256
#define ND 128
#define NN 3072
#define BN_EPS 1e-5f
#define MSPLIT 24   /* K split count for the Mbuf GEMM: 3072/24 = 128 per slice */

static __device__ __forceinline__ short f2s(float v) {
    bf16 h = __float2bfloat16(v);
    return *reinterpret_cast<short*>(&h);
}

// Setup: blocks 0..383 build Wall[r][c] = [phi_w; g_w; theta_w] bf16 and
// bcat384[r] = [phi_b; g_b; theta_b]; block 0 also folds BN (invv, bias2);
// blocks 384..1407 zero Mbuf (replaces hipMemsetAsync dispatch).
__global__ __launch_bounds__(256) void setup_kernel(
    const float* __restrict__ phi_w, const float* __restrict__ g_w,
    const float* __restrict__ theta_w,
    const float* __restrict__ phi_b, const float* __restrict__ g_b,
    const float* __restrict__ theta_b,
    const float* __restrict__ w_b, const float* __restrict__ gamma,
    const float* __restrict__ beta, const float* __restrict__ mean,
    const float* __restrict__ var,
    short* __restrict__ Wall, float* __restrict__ bcat384,
    float* __restrict__ invv, float* __restrict__ bias2,
    float* __restrict__ Mbuf)
{
    int t = threadIdx.x;
    int r = blockIdx.x;
    if (r < 384) {
        const float* src = (r < ND) ? (phi_w + (size_t)r * NC)
                         : (r < NC) ? (g_w + (size_t)(r - ND) * NC)
                                    : (theta_w + (size_t)(r - NC) * NC);
        Wall[(size_t)r * NC + t] = f2s(src[t]);
        if (t == 0)
            bcat384[r] = (r < ND) ? phi_b[r]
                       : (r < NC) ? g_b[r - ND] : theta_b[r - NC];
        if (r == 0) {
            float iv = gamma[t] * rsqrtf(var[t] + BN_EPS);
            invv[t] = iv;
            bias2[t] = iv * (w_b[t] - mean[t]) + beta[t];
        }
    } else {
        // zero Mbuf: 1024 blocks x 256 threads x 4 floats = 1,048,576 = 8*128*128
        floatx4 z = {0.f, 0.f, 0.f, 0.f};
        *(floatx4*)(Mbuf + ((size_t)(r - 384) * 256 + t) * 4) = z;
    }
}

// Fused projection: reads x (fp32, (B,C,N)) ONCE, produces
//   projbuf[b][r][n] (r<256: phi rows 0-127, g rows 128-255), n-contig bf16
//   thND[b][n][d]    (theta rows, transposed layout), d-contig bf16
// Block: 768 threads = 12 waves of 64x64 tiles; M-tile = 384 (all proj rows),
// n-tile = 128; K = C = 256 in 4 chunks of 64. x-chunk is converted to bf16
// and LDS-transposed during staging (pad 72: verified ds_read_b128 geometry).
// A-fragments come straight from global Wall (192 KB, L2-resident).
__global__ __launch_bounds__(768)
void proj_kernel(const float* __restrict__ x, const short* __restrict__ Wall,
                 const float* __restrict__ bcat384,
                 short* __restrict__ projbuf, short* __restrict__ thND)
{
    __shared__ short Xs[128][72];   // [n][c-chunk], c contiguous
    int b = blockIdx.y;
    int n0 = blockIdx.x * 128;
    int t = threadIdx.x;
    int lane = t & 63;
    int wave = t >> 6;              // 0..11
    int wm = wave >> 1;             // 0..5  (64-row group of the 384 rows)
    int wn = wave & 1;              // 0..1  (64-col group of the 128 n)
    int lm = lane & 15;
    int lk = (lane >> 4) * 8;
    int sn = t & 127;               // staging: n index
    int scg = t >> 7;               // staging: c-group (active if <4)

    const float* xb = x + (size_t)b * NC * NN;

    floatx4 zero = {0.f, 0.f, 0.f, 0.f};
    floatx4 acc[4][4];
#pragma unroll
    for (int i = 0; i < 4; ++i)
#pragma unroll
        for (int j = 0; j < 4; ++j) acc[i][j] = zero;

    for (int kt = 0; kt < NC; kt += 64) {
        __syncthreads();
        if (scg < 4) {
            const float* src = xb + (size_t)(kt + scg * 16) * NN + n0 + sn;
            float v[16];
#pragma unroll
            for (int j = 0; j < 16; ++j) v[j] = src[(size_t)j * NN];
            short8 s0, s1;
#pragma unroll
            for (int j = 0; j < 8; ++j) { s0[j] = f2s(v[j]); s1[j] = f2s(v[8 + j]); }
            *(short8*)&Xs[sn][scg * 16]     = s0;
            *(short8*)&Xs[sn][scg * 16 + 8] = s1;
        }
        __syncthreads();
#pragma unroll
        for (int kk = 0; kk < 64; kk += 32) {
            short8 af[4], bfr[4];
#pragma unroll
            for (int i = 0; i < 4; ++i)
                af[i] = *(const short8*)(Wall +
                        (size_t)(wm * 64 + i * 16 + lm) * NC + kt + kk + lk);
#pragma unroll
            for (int j = 0; j < 4; ++j)
                bfr[j] = *(const short8*)&Xs[wn * 64 + j * 16 + lm][kk + lk];
#pragma unroll
            for (int i = 0; i < 4; ++i)
#pragma unroll
                for (int j = 0; j < 4; ++j)
                    acc[i][j] = __builtin_amdgcn_mfma_f32_16x16x32_bf16(
                        af[i], bfr[j], acc[i][j], 0, 0, 0);
        }
    }

    // C/D layout: col = lane&15, row = (lane>>4)*4 + reg
    int row0 = wm * 64 + (lane >> 4) * 4;
    int col0 = n0 + wn * 64 + lm;

    if (wm < 4) {   // phi/g rows -> projbuf[r][n], row-major (coalesced 64B)
        short* Cb = projbuf + (size_t)b * NC * NN;
#pragma unroll
        for (int i = 0; i < 4; ++i) {
#pragma unroll
            for (int r = 0; r < 4; ++r) {
                int row = row0 + i * 16 + r;
                float bv = bcat384[row];
#pragma unroll
                for (int j = 0; j < 4; ++j)
                    Cb[(size_t)row * NN + col0 + j * 16] =
                        f2s(acc[i][j][r] + bv);
            }
        }
    } else {        // theta rows -> thND[n][d] (transposed scatter; L2 merges)
        short* Tb = thND + (size_t)b * NN * ND;
#pragma unroll
        for (int i = 0; i < 4; ++i) {
#pragma unroll
            for (int r = 0; r < 4; ++r) {
                int d = row0 - 256 + i * 16 + r;
                float bv = bcat384[256 + d];
#pragma unroll
                for (int j = 0; j < 4; ++j)
                    Tb[(size_t)(col0 + j * 16) * ND + d] =
                        f2s(acc[i][j][r] + bv);
            }
        }
    }
}

// C(M,N) = A(M,K) . B(N,K)^T  (bf16 operands, K contiguous), per-batch
// strides in elements. 128x128 tile, 4 waves, BK=64, fp32 accumulate.
// mode 3 (the only one used now): f32 out = acc + bias[row] + resid.
__global__ __launch_bounds__(256)
void bt_gemm(const short* __restrict__ Ag0, const short* __restrict__ Bg0,
             void* __restrict__ Cout, const float* __restrict__ bias,
             const float* __restrict__ resid,
             int M, int N, int K,
             long sA, long sB, long sC, long sR,
             int mode)
{
    __shared__ short As[128][72];
    __shared__ short Bs[128][72];
    int b = blockIdx.z;
    const short* Ag = Ag0 + (size_t)b * sA;
    const short* Bg = Bg0 + (size_t)b * sB;
    int tile_m = blockIdx.y * 128;
    int tile_n = blockIdx.x * 128;
    int t = threadIdx.x;
    int lane = t & 63;
    int wave = t >> 6;
    int wr = wave >> 1, wc = wave & 1;
    int lm = lane & 15;
    int lk = (lane >> 4) * 8;
    int ch = (t & 7) * 8;
    int r0 = t >> 3;

    floatx4 zero = {0.f, 0.f, 0.f, 0.f};
    floatx4 acc[4][4];
#pragma unroll
    for (int i = 0; i < 4; ++i)
#pragma unroll
        for (int j = 0; j < 4; ++j) acc[i][j] = zero;

    for (int kt = 0; kt < K; kt += 64) {
        __syncthreads();
#pragma unroll
        for (int p = 0; p < 4; ++p) {
            int r = r0 + p * 32;
            *(short8*)&As[r][ch] = *(const short8*)(Ag + (size_t)(tile_m + r) * K + kt + ch);
            *(short8*)&Bs[r][ch] = *(const short8*)(Bg + (size_t)(tile_n + r) * K + kt + ch);
        }
        __syncthreads();
#pragma unroll
        for (int kk = 0; kk < 64; kk += 32) {
            short8 af[4], bfr[4];
#pragma unroll
            for (int i = 0; i < 4; ++i)
                af[i] = *(const short8*)&As[wr * 64 + i * 16 + lm][kk + lk];
#pragma unroll
            for (int j = 0; j < 4; ++j)
                bfr[j] = *(const short8*)&Bs[wc * 64 + j * 16 + lm][kk + lk];
#pragma unroll
            for (int i = 0; i < 4; ++i)
#pragma unroll
                for (int j = 0; j < 4; ++j)
                    acc[i][j] = __builtin_amdgcn_mfma_f32_16x16x32_bf16(
                        af[i], bfr[j], acc[i][j], 0, 0, 0);
        }
    }

    int row0 = tile_m + wr * 64 + (lane >> 4) * 4;
    int col0 = tile_n + wc * 64 + lm;

    if (mode == 3) { // fp32 out = acc + bias2[row] + resid
        float* Cf = (float*)Cout + (size_t)b * sC;
        const float* Rg = resid + (size_t)b * sR;
#pragma unroll
        for (int i = 0; i < 4; ++i) {
#pragma unroll
            for (int r = 0; r < 4; ++r) {
                int row = row0 + i * 16 + r;
                float bv = bias[row];
#pragma unroll
                for (int j = 0; j < 4; ++j) {
                    size_t idx = (size_t)row * N + col0 + j * 16;
                    Cf[idx] = acc[i][j][r] + bv + Rg[idx];
                }
            }
        }
    }
}

// Split-K GEMM: Mbuf[b][i][j] += scale * sum_{k in slice} phi[i][k]*g[j][k]
// grid (MSPLIT, 1, NB); Mbuf zeroed by setup_kernel.
__global__ __launch_bounds__(256)
void mbuf_split(const short* __restrict__ projbuf, float* __restrict__ Mbuf,
                float scale)
{
    __shared__ short As[128][72];
    __shared__ short Bs[128][72];
    int b = blockIdx.z;
    const short* Ag = projbuf + (size_t)b * NC * NN;   // phi rows (D x N)
    const short* Bg = Ag + (size_t)ND * NN;            // g rows (D x N)
    int kt0 = blockIdx.x * (NN / MSPLIT);
    int t = threadIdx.x;
    int lane = t & 63;
    int wave = t >> 6;
    int wr = wave >> 1, wc = wave & 1;
    int lm = lane & 15;
    int lk = (lane >> 4) * 8;
    int ch = (t & 7) * 8;
    int r0 = t >> 3;

    floatx4 zero = {0.f, 0.f, 0.f, 0.f};
    floatx4 acc[4][4];
#pragma unroll
    for (int i = 0; i < 4; ++i)
#pragma unroll
        for (int j = 0; j < 4; ++j) acc[i][j] = zero;

    for (int kt = kt0; kt < kt0 + NN / MSPLIT; kt += 64) {
        __syncthreads();
#pragma unroll
        for (int p = 0; p < 4; ++p) {
            int r = r0 + p * 32;
            *(short8*)&As[r][ch] = *(const short8*)(Ag + (size_t)r * NN + kt + ch);
            *(short8*)&Bs[r][ch] = *(const short8*)(Bg + (size_t)r * NN + kt + ch);
        }
        __syncthreads();
#pragma unroll
        for (int kk = 0; kk < 64; kk += 32) {
            short8 af[4], bfr[4];
#pragma unroll
            for (int i = 0; i < 4; ++i)
                af[i] = *(const short8*)&As[wr * 64 + i * 16 + lm][kk + lk];
#pragma unroll
            for (int j = 0; j < 4; ++j)
                bfr[j] = *(const short8*)&Bs[wc * 64 + j * 16 + lm][kk + lk];
#pragma unroll
            for (int i = 0; i < 4; ++i)
#pragma unroll
                for (int j = 0; j < 4; ++j)
                    acc[i][j] = __builtin_amdgcn_mfma_f32_16x16x32_bf16(
                        af[i], bfr[j], acc[i][j], 0, 0, 0);
        }
    }

    float* Mf = Mbuf + (size_t)b * ND * ND;
    int row0 = wr * 64 + (lane >> 4) * 4;
    int col0 = wc * 64 + lm;
#pragma unroll
    for (int i = 0; i < 4; ++i)
#pragma unroll
        for (int j = 0; j < 4; ++j)
#pragma unroll
            for (int r = 0; r < 4; ++r)
                atomicAdd(&Mf[(size_t)(row0 + i * 16 + r) * ND + col0 + j * 16],
                          acc[i][j][r] * scale);
}

// P2[b][c][e] = inv[c] * sum_d w_w[c][d] * Mbuf[b][e][d]   (bf16 out)
__global__ __launch_bounds__(256)
void p2_kernel(const float* __restrict__ w_w, const float* __restrict__ Mbuf,
               const float* __restrict__ invv, short* __restrict__ P2)
{
    int b = blockIdx.y;
    int t = threadIdx.x;
    int c = blockIdx.x * 2 + (t >> 7);
    int e = t & 127;
    const float* wrow = w_w + (size_t)c * ND;
    const float* Mr = Mbuf + (size_t)b * ND * ND + (size_t)e * ND;
    float s = 0.f;
#pragma unroll 4
    for (int d = 0; d < ND; ++d) s += wrow[d] * Mr[d];
    P2[(size_t)b * NC * ND + (size_t)c * ND + e] = f2s(s * invv[c]);
}

extern "C" void kernel_launch(void* const* d_in, const int* in_sizes, int n_in,
                              void* d_out, int out_size, void* d_ws, size_t ws_size,
                              hipStream_t stream)
{
    const float* x       = (const float*)d_in[0];
    const float* g_w     = (const float*)d_in[1];
    const float* g_b     = (const float*)d_in[2];
    const float* theta_w = (const float*)d_in[3];
    const float* theta_b = (const float*)d_in[4];
    const float* phi_w   = (const float*)d_in[5];
    const float* phi_b   = (const float*)d_in[6];
    const float* w_w     = (const float*)d_in[7];
    const float* w_b     = (const float*)d_in[8];
    const float* gamma   = (const float*)d_in[9];
    const float* beta    = (const float*)d_in[10];
    const float* mean    = (const float*)d_in[11];
    const float* var     = (const float*)d_in[12];
    (void)in_sizes; (void)n_in; (void)out_size; (void)ws_size;

    char* w = (char*)d_ws;
    short* Wall   = (short*)w; w += (size_t)384 * NC * 2;
    float* bcat384= (float*)w; w += (size_t)384 * 4;
    float* invv   = (float*)w; w += (size_t)NC * 4;
    float* bias2  = (float*)w; w += (size_t)NC * 4;
    w = (char*)(((size_t)w + 255) & ~(size_t)255);
    short* projbuf= (short*)w; w += (size_t)NB * NC * NN * 2;  // (B,[phi;g],N)
    short* thND   = (short*)w; w += (size_t)NB * NN * ND * 2;  // (B,N,D)
    float* Mbuf   = (float*)w; w += (size_t)NB * ND * ND * 4;  // (B,D,D)
    short* P2     = (short*)w; w += (size_t)NB * NC * ND * 2;  // (B,C,D)

    // 1. setup: Wall/biases/BN-fold + zero Mbuf
    setup_kernel<<<dim3(384 + 1024), dim3(256), 0, stream>>>(
        phi_w, g_w, theta_w, phi_b, g_b, theta_b, w_b, gamma, beta, mean, var,
        Wall, bcat384, invv, bias2, Mbuf);

    // 2. fused projection (reads x exactly once)
    proj_kernel<<<dim3(NN / 128, NB), dim3(768), 0, stream>>>(
        x, Wall, bcat384, projbuf, thND);

    // 3. Mbuf (128x128 f32) = phi . g^T / N   -- split-K, atomics
    mbuf_split<<<dim3(MSPLIT, 1, NB), 256, 0, stream>>>(
        projbuf, Mbuf, 1.f / (float)NN);

    // 4. P2 = inv * (w_w . M^T)
    p2_kernel<<<dim3(NC / 2, NB), 256, 0, stream>>>(w_w, Mbuf, invv, P2);

    // 5. out (256x3072 f32) = P2 (256x128) . thND^T + bias2 + x
    bt_gemm<<<dim3(NN / 128, NC / 128, NB), 256, 0, stream>>>(
        P2, thND, d_out, bias2, x,
        NC, NN, ND, (long)NC * ND, (long)NN * ND, (long)NC * NN, (long)NC * NN,
        3);
}